// Round 5
// baseline (105.790 us; speedup 1.0000x reference)
//
#include <hip/hip_runtime.h>

// Problem constants
#define NB   4096   // B
#define ND   256    // D
#define N2B  8192   // 2B
#define INV_T 2.0f  // 1/TEMP, TEMP=0.5

typedef __attribute__((ext_vector_type(8))) short bf16x8;
typedef __attribute__((ext_vector_type(16))) float f32x16;

__device__ __forceinline__ void gload_lds16(const void* g, void* l) {
  __builtin_amdgcn_global_load_lds(
      (const __attribute__((address_space(1))) void*)g,
      (__attribute__((address_space(3))) void*)l, 16, 0, 0);
}

// fp32 -> bf16 (RNE) as raw bits
__device__ __forceinline__ unsigned short f2b(float f) {
  unsigned int u = __float_as_uint(f);
  u = (u + 0x7fffu + ((u >> 16) & 1u)) >> 16;
  return (unsigned short)u;
}
__device__ __forceinline__ float b2f(unsigned short h) {
  return __uint_as_float(((unsigned int)h) << 16);
}

// Kernel A: L2-normalize rows of [x_i; x_j] -> Z (bf16 bits).
//   diagE[zrow] = exp(diag/T)   (self term, subtracted in k_final)
//   pos[r] = dot(z_i[r], z_j[r]) (LDS exchange between i- and j-waves)
// Block 0 zero-inits lossAcc and ticket.
__global__ __launch_bounds__(256) void k_normalize(
    const float* __restrict__ xi, const float* __restrict__ xj,
    unsigned short* __restrict__ Z, float* __restrict__ diagE,
    float* __restrict__ pos, float* __restrict__ lossAcc,
    unsigned int* __restrict__ ticket) {
  __shared__ float sh[2][256];
  if (blockIdx.x == 0 && threadIdx.x == 0) { *lossAcc = 0.0f; *ticket = 0u; }
  int wave = threadIdx.x >> 6, lane = threadIdx.x & 63;
  int r = (int)blockIdx.x * 2 + (wave & 1);  // row in [0, NB)
  bool isJ = wave >= 2;
  const float* src = (isJ ? xj : xi) + (size_t)r * ND;
  int zrow = r + (isJ ? NB : 0);

  float4 v = *(const float4*)(src + lane * 4);
  float ss = v.x * v.x + v.y * v.y + v.z * v.z + v.w * v.w;
#pragma unroll
  for (int m = 1; m < 64; m <<= 1) ss += __shfl_xor(ss, m, 64);
  float scale = 1.0f / fmaxf(sqrtf(ss), 1e-12f);
  unsigned short h0 = f2b(v.x * scale), h1 = f2b(v.y * scale);
  unsigned short h2 = f2b(v.z * scale), h3 = f2b(v.w * scale);
  ushort4 st; st.x = h0; st.y = h1; st.z = h2; st.w = h3;
  *(ushort4*)(Z + (size_t)zrow * ND + lane * 4) = st;

  float f0 = b2f(h0), f1 = b2f(h1), f2 = b2f(h2), f3 = b2f(h3);
  float d = f0 * f0 + f1 * f1 + f2 * f2 + f3 * f3;
#pragma unroll
  for (int m = 1; m < 64; m <<= 1) d += __shfl_xor(d, m, 64);
  if (lane == 0) diagE[zrow] = __expf(d * INV_T);

  if (isJ) {
    float* s = sh[wave & 1] + lane * 4;
    s[0] = f0; s[1] = f1; s[2] = f2; s[3] = f3;
  }
  __syncthreads();
  if (!isJ) {
    const float* s = sh[wave] + lane * 4;
    float p = f0 * s[0] + f1 * s[1] + f2 * s[2] + f3 * s[3];
#pragma unroll
    for (int m = 1; m < 64; m <<= 1) p += __shfl_xor(p, m, 64);
    if (lane == 0) pos[r] = p;
  }
}

// Kernel B: A-stationary band GEMM, 32x32x16 MFMA, dbuf-pipelined staging.
// Grid 512 = 32 row-bands (256 rows) x 16 col-spans (512 cols, 8 tiles of 64).
// Wave owns 64 A-rows (2 reg-groups of 32) fully in registers (128 VGPRs).
// B streams through ping-pong LDS tiles (2 x 32 KB); batch t+1's 8 lds-dma
// calls remain in flight across compute of tile t (s_waitcnt vmcnt(8)).
// Per-wave LDS ingest = 64 cols x 256 K x 2 B = 32 KB/tile; amplification 2x
// (was 4x in R4). Rowsum partials complete in-block -> R[row][16], no atomics.
__global__ __launch_bounds__(256, 2) void k_gemm_exp(
    const unsigned short* __restrict__ Z, float* __restrict__ R) {
  __shared__ alignas(16) unsigned short Bs[2][64 * ND];  // 2 x 32 KiB

  int tid = threadIdx.x;
  int wave = tid >> 6, lane = tid & 63;
  int r5 = lane & 31, h = lane >> 5;
  int band = (int)blockIdx.x >> 4;   // 0..31
  int span = (int)blockIdx.x & 15;   // 0..15
  int rowA = band * 256 + wave * 64;
  int colspan = span * 512;

  // A fragments: 2 row-groups x 16 k-steps, layout A[m=r5][k=h*8+j]
  bf16x8 afr[2][16];
#pragma unroll
  for (int rg = 0; rg < 2; ++rg)
#pragma unroll
    for (int kk = 0; kk < 16; ++kk)
      afr[rg][kk] = *(const bf16x8*)(Z + (size_t)(rowA + rg * 32 + r5) * ND +
                                     kk * 16 + h * 8);

  float rs[2][16];
#pragma unroll
  for (int rg = 0; rg < 2; ++rg)
#pragma unroll
    for (int g = 0; g < 16; ++g) rs[rg][g] = 0.0f;

  // stage batch t into buffer b: 8 calls/wave, 1 KB each (2 Z-rows).
  // Source chunk XOR-swizzled by (ldsrow & 31); dest is lane-linear (DMA).
#define STAGE(t, b)                                                         \
  {                                                                         \
    int colbase = colspan + (t)*64;                                         \
    _Pragma("unroll") for (int call = 0; call < 8; ++call) {                \
      int r0 = wave * 16 + call * 2;                                        \
      int zr = colbase + r0 + h;                                            \
      int gc = r5 ^ (zr & 31);                                              \
      gload_lds16(Z + (size_t)zr * ND + gc * 8, &Bs[b][r0 * ND]);           \
    }                                                                       \
  }

  STAGE(0, 0)
  STAGE(1, 1)

#pragma unroll
  for (int t = 0; t < 8; ++t) {
    if (t < 7)
      asm volatile("s_waitcnt vmcnt(8)" ::: "memory");
    else
      asm volatile("s_waitcnt vmcnt(0)" ::: "memory");
    __syncthreads();

    const unsigned short* Bb = &Bs[t & 1][0];
#pragma unroll
    for (int ni = 0; ni < 2; ++ni) {
      f32x16 acc0 = {};
      f32x16 acc1 = {};
#pragma unroll
      for (int kk = 0; kk < 16; ++kk) {
        // B[n=r5][k=h*8+j] at k-step kk; slot swizzle ^(row&31)=^r5
        bf16x8 bf =
            *(const bf16x8*)&Bb[(ni * 32 + r5) * ND + (((kk * 2 + h) ^ r5) * 8)];
        acc0 = __builtin_amdgcn_mfma_f32_32x32x16_bf16(afr[0][kk], bf, acc0, 0,
                                                       0, 0);
        acc1 = __builtin_amdgcn_mfma_f32_32x32x16_bf16(afr[1][kk], bf, acc1, 0,
                                                       0, 0);
      }
#pragma unroll
      for (int g = 0; g < 16; ++g) {
        rs[0][g] += __expf(acc0[g] * INV_T);
        rs[1][g] += __expf(acc1[g] * INV_T);
      }
    }
    __syncthreads();
    if (t + 2 < 8) STAGE(t + 2, t & 1)
  }

  // Reduce across the 32 col-lanes (C/D col = lane&31): masks 1..16.
#pragma unroll
  for (int m = 1; m <= 16; m <<= 1)
#pragma unroll
    for (int rg = 0; rg < 2; ++rg)
#pragma unroll
      for (int g = 0; g < 16; ++g)
        rs[rg][g] += __shfl_xor(rs[rg][g], m, 64);

  // C/D row = (reg&3) + 8*(reg>>2) + 4*h (+ rg*32). Writer: r5 == reg.
#pragma unroll
  for (int rg = 0; rg < 2; ++rg)
#pragma unroll
    for (int g = 0; g < 16; ++g)
      if (r5 == g) {
        int rowIn = (g & 3) + 8 * (g >> 2) + 4 * h;
        R[(size_t)(rowA + rg * 32 + rowIn) * 16 + span] = rs[rg][g];
      }
#undef STAGE
}

// Kernel C: 32 blocks x 256 rows. rowsum[r] = sum_{q<16} R[r][q] - diagE[r];
// term = log(rowsum) - pos[r%B]/T. Block-reduce -> one atomicAdd per block;
// ticketed last block writes out = lossAcc / 2B.
__global__ __launch_bounds__(256) void k_final(
    const float* __restrict__ R, const float* __restrict__ diagE,
    const float* __restrict__ pos, float* __restrict__ lossAcc,
    unsigned int* __restrict__ ticket, float* __restrict__ out) {
  __shared__ float red[4];
  int tid = threadIdx.x;
  int wave = tid >> 6, lane = tid & 63;
  int row = (int)blockIdx.x * 256 + tid;

  const float* Rr = R + (size_t)row * 16;
  float s = -diagE[row];
#pragma unroll
  for (int i = 0; i < 4; ++i) {
    float4 a = *(const float4*)(Rr + i * 4);
    s += (a.x + a.y) + (a.z + a.w);
  }
  float term = __logf(s) - INV_T * pos[row & (NB - 1)];
#pragma unroll
  for (int m = 1; m < 64; m <<= 1) term += __shfl_xor(term, m, 64);
  if (lane == 0) red[wave] = term;
  __syncthreads();
  if (tid == 0) {
    float bs = red[0] + red[1] + red[2] + red[3];
    atomicAdd(lossAcc, bs);
    __threadfence();
    unsigned int old = atomicAdd(ticket, 1u);
    if (old == 31u) {
      float v = atomicAdd(lossAcc, 0.0f);  // atomic read after all adds
      out[0] = v * (1.0f / (float)N2B);
    }
  }
}

extern "C" void kernel_launch(void* const* d_in, const int* in_sizes, int n_in,
                              void* d_out, int out_size, void* d_ws,
                              size_t ws_size, hipStream_t stream) {
  const float* xi = (const float*)d_in[0];
  const float* xj = (const float*)d_in[1];
  float* out = (float*)d_out;
  char* ws = (char*)d_ws;
  unsigned short* Z = (unsigned short*)ws;           // 4 MiB
  float* R = (float*)(ws + (4u << 20));              // 8192*16*4 = 512 KiB
  float* pos = (float*)(ws + (8u << 20));            // 16 KiB
  float* diagE = (float*)(ws + (8u << 20) + 65536);  // 32 KiB
  float* lossAcc = (float*)(ws + (8u << 20) + 131072);
  unsigned int* ticket = (unsigned int*)(ws + (8u << 20) + 131072 + 64);

  k_normalize<<<dim3(NB / 2), dim3(256), 0, stream>>>(xi, xj, Z, diagE, pos,
                                                      lossAcc, ticket);
  k_gemm_exp<<<dim3(512), dim3(256), 0, stream>>>(Z, R);
  k_final<<<dim3(32), dim3(256), 0, stream>>>(R, diagE, pos, lossAcc, ticket,
                                              out);
}